// Round 7
// baseline (361.234 us; speedup 1.0000x reference)
//
#include <hip/hip_runtime.h>
#include <hip/hip_bf16.h>

#define HID 1024
#define NHEAD 16
#define HDIM 64
#define BB 4
#define SS 2048
#define MTOK (BB * SS)   // 8192 tokens
#define KVB 128

// 0.125 * log2(e): folded into Q at the qkv epilogue so attn softmax is a single v_exp_f32 (2^x)
#define QSCALE 0.18033688011112042f

typedef __attribute__((ext_vector_type(8))) short bf16x8;
typedef __attribute__((ext_vector_type(4))) float f32x4;
typedef __attribute__((ext_vector_type(16))) float f32x16;
typedef __attribute__((ext_vector_type(4))) unsigned int u32x4;

__device__ __forceinline__ unsigned short f2bs(float f) {
  __hip_bfloat16 h = __float2bfloat16(f);
  unsigned short u;
  __builtin_memcpy(&u, &h, 2);
  return u;
}

// async global->LDS, 16B per lane. LDS dest = wave-uniform base + lane*16.
__device__ __forceinline__ void gload16(const void* g, void* l) {
  __builtin_amdgcn_global_load_lds((__attribute__((address_space(1))) const void*)g,
                                   (__attribute__((address_space(3))) void*)l, 16, 0, 0);
}

// ===================== conversion pass (fp32 -> bf16, + mask prep) =====================
__global__ __launch_bounds__(256) void cvt_all(
    const float* __restrict__ s_q, const float* __restrict__ s_k, const float* __restrict__ s_v,
    const float* __restrict__ wq, const float* __restrict__ wk, const float* __restrict__ wv,
    const float* __restrict__ wo, const float* __restrict__ mask,
    unsigned short* __restrict__ xq, unsigned short* __restrict__ xk, unsigned short* __restrict__ xv,
    unsigned short* __restrict__ wcat, unsigned short* __restrict__ wobf,
    float* __restrict__ mvec8) {
  const int bid = blockIdx.x;
  if (bid >= 3584) {
    // mvec8[b][s] = ((1-mask)*(-10000) - 8) * log2(e)   (C-init for QK MFMA, log2-domain)
    const int i = (bid - 3584) * 1024 + threadIdx.x * 4;
    float4 f = *(const float4*)(mask + i);
    float4 o;
    o.x = (f.x - 1.0f) * 14426.9504f - 11.5415603f;
    o.y = (f.y - 1.0f) * 14426.9504f - 11.5415603f;
    o.z = (f.z - 1.0f) * 14426.9504f - 11.5415603f;
    o.w = (f.w - 1.0f) * 14426.9504f - 11.5415603f;
    *(float4*)(mvec8 + i) = o;
    return;
  }
  const float* src;
  unsigned short* dst;
  size_t off;
  if (bid < 3072) {
    int s = bid >> 10;
    src = (s == 0 ? s_q : (s == 1 ? s_k : s_v));
    dst = (s == 0 ? xq : (s == 1 ? xk : xv));
    off = (size_t)(bid & 1023) * 8192;
  } else {
    int s = (bid - 3072) >> 7;
    src = (s == 0 ? wq : (s == 1 ? wk : (s == 2 ? wv : wo)));
    dst = (s < 3 ? wcat + (size_t)s * HID * HID : wobf);
    off = (size_t)((bid - 3072) & 127) * 8192;
  }
  src += off;
  dst += off;
  const int t = threadIdx.x;
#pragma unroll
  for (int i = 0; i < 8; i++) {
    float4 f = *(const float4*)(src + (size_t)(i * 256 + t) * 4);
    ushort4 h;
    h.x = f2bs(f.x); h.y = f2bs(f.y); h.z = f2bs(f.z); h.w = f2bs(f.w);
    *(ushort4*)(dst + (size_t)(i * 256 + t) * 4) = h;
  }
}

// standalone mask prep (fallback path)
__global__ __launch_bounds__(256) void prep_mask(const float* __restrict__ mask,
                                                 float* __restrict__ mvec8) {
  const int i = blockIdx.x * 1024 + threadIdx.x * 4;
  float4 f = *(const float4*)(mask + i);
  float4 o;
  o.x = (f.x - 1.0f) * 14426.9504f - 11.5415603f;
  o.y = (f.y - 1.0f) * 14426.9504f - 11.5415603f;
  o.z = (f.z - 1.0f) * 14426.9504f - 11.5415603f;
  o.w = (f.w - 1.0f) * 14426.9504f - 11.5415603f;
  *(float4*)(mvec8 + i) = o;
}

// ===================== fused QKV GEMM (bf16, global_load_lds) =====================
__global__ __launch_bounds__(256) void qkv_gemm(
    const unsigned short* __restrict__ xq, const unsigned short* __restrict__ xk,
    const unsigned short* __restrict__ xv, const unsigned short* __restrict__ wcat,
    const float* __restrict__ bq, const float* __restrict__ bk, const float* __restrict__ bv,
    unsigned short* __restrict__ qhm, unsigned short* __restrict__ khm,
    unsigned short* __restrict__ vth) {
  __shared__ unsigned short As[128 * 32];
  __shared__ unsigned short Bs[128 * 32];
  const int bid = blockIdx.x;
  const int mt = bid / 24, nt = bid % 24;
  const int sel = nt >> 3;
  const int m0 = mt << 7, n0 = (nt & 7) << 7;
  const int tid = threadIdx.x;
  const int lane = tid & 63, wave = tid >> 6;
  const int quad = lane >> 4, l15 = lane & 15;
  const int wm = ((wave >> 1) << 6), wn = ((wave & 1) << 6);

  const unsigned short* A = (sel == 0 ? xq : (sel == 1 ? xk : xv));
  const unsigned short* W = wcat + (size_t)sel * HID * HID;
  const float* bias = (sel == 0 ? bq : (sel == 1 ? bk : bv));
  const float osc = (sel == 0 ? QSCALE : 1.0f);

  const int c0 = wave * 128 + lane;
  const int c1 = c0 + 64;
  const unsigned short* gA0 = A + (size_t)(m0 + (c0 >> 2)) * HID + (c0 & 3) * 8;
  const unsigned short* gA1 = A + (size_t)(m0 + (c1 >> 2)) * HID + (c1 & 3) * 8;
  const unsigned short* gB0 = W + (size_t)(n0 + (c0 >> 2)) * HID + (c0 & 3) * 8;
  const unsigned short* gB1 = W + (size_t)(n0 + (c1 >> 2)) * HID + (c1 & 3) * 8;
  unsigned short* lA0 = As + (size_t)(wave * 128) * 8;
  unsigned short* lA1 = lA0 + 64 * 8;
  unsigned short* lB0 = Bs + (size_t)(wave * 128) * 8;
  unsigned short* lB1 = lB0 + 64 * 8;

  f32x4 acc[4][4] = {};

  for (int k0 = 0; k0 < HID; k0 += 32) {
    __syncthreads();
    gload16(gA0 + k0, lA0);
    gload16(gA1 + k0, lA1);
    gload16(gB0 + k0, lB0);
    gload16(gB1 + k0, lB1);
    __syncthreads();
    bf16x8 af[4], bfr[4];
#pragma unroll
    for (int i = 0; i < 4; i++)
      af[i] = *(const bf16x8*)(As + (wm + i * 16 + l15) * 32 + quad * 8);
#pragma unroll
    for (int j = 0; j < 4; j++)
      bfr[j] = *(const bf16x8*)(Bs + (wn + j * 16 + l15) * 32 + quad * 8);
#pragma unroll
    for (int i = 0; i < 4; i++)
#pragma unroll
      for (int j = 0; j < 4; j++)
        acc[i][j] = __builtin_amdgcn_mfma_f32_16x16x32_bf16(af[i], bfr[j], acc[i][j], 0, 0, 0);
  }

#pragma unroll
  for (int j = 0; j < 4; j++) {
    const int col = n0 + wn + j * 16 + l15;
    const float bvv = bias[col];
    const int hh = col >> 6, d = col & 63;
    if (sel < 2) {
      unsigned short* outp = (sel == 0 ? qhm : khm);
#pragma unroll
      for (int i = 0; i < 4; i++) {
        const int row0 = m0 + wm + i * 16 + quad * 4;
        const int bb = row0 >> 11, s0 = row0 & 2047;
        const size_t base = ((size_t)(bb * NHEAD + hh)) * SS * HDIM + (size_t)s0 * HDIM + d;
#pragma unroll
        for (int r = 0; r < 4; r++)
          outp[base + (size_t)r * HDIM] = f2bs((acc[i][j][r] + bvv) * osc);
      }
    } else {
#pragma unroll
      for (int i = 0; i < 4; i++) {
        const int row0 = m0 + wm + i * 16 + quad * 4;
        const int bb = row0 >> 11, s0 = row0 & 2047;
        ushort4 pk;
        pk.x = f2bs(acc[i][j][0] + bvv);
        pk.y = f2bs(acc[i][j][1] + bvv);
        pk.z = f2bs(acc[i][j][2] + bvv);
        pk.w = f2bs(acc[i][j][3] + bvv);
        *(ushort4*)&vth[((size_t)(bb * NHEAD + hh)) * HDIM * SS + (size_t)d * SS + s0] = pk;
      }
    }
  }
}

// ===================== out-proj GEMM (bf16 A/W, fp32 out) =====================
__global__ __launch_bounds__(256) void out_gemm(const unsigned short* __restrict__ A,
                                                const unsigned short* __restrict__ W,
                                                const float* __restrict__ bias,
                                                float* __restrict__ C) {
  __shared__ unsigned short As[128 * 32];
  __shared__ unsigned short Bs[128 * 32];
  const int bid = blockIdx.x;
  const int mt = bid >> 3, nt = bid & 7;
  const int m0 = mt << 7, n0 = nt << 7;
  const int tid = threadIdx.x;
  const int lane = tid & 63, wave = tid >> 6;
  const int quad = lane >> 4, l15 = lane & 15;
  const int wm = ((wave >> 1) << 6), wn = ((wave & 1) << 6);

  const int c0 = wave * 128 + lane;
  const int c1 = c0 + 64;
  const unsigned short* gA0 = A + (size_t)(m0 + (c0 >> 2)) * HID + (c0 & 3) * 8;
  const unsigned short* gA1 = A + (size_t)(m0 + (c1 >> 2)) * HID + (c1 & 3) * 8;
  const unsigned short* gB0 = W + (size_t)(n0 + (c0 >> 2)) * HID + (c0 & 3) * 8;
  const unsigned short* gB1 = W + (size_t)(n0 + (c1 >> 2)) * HID + (c1 & 3) * 8;
  unsigned short* lA0 = As + (size_t)(wave * 128) * 8;
  unsigned short* lA1 = lA0 + 64 * 8;
  unsigned short* lB0 = Bs + (size_t)(wave * 128) * 8;
  unsigned short* lB1 = lB0 + 64 * 8;

  f32x4 acc[4][4] = {};

  for (int k0 = 0; k0 < HID; k0 += 32) {
    __syncthreads();
    gload16(gA0 + k0, lA0);
    gload16(gA1 + k0, lA1);
    gload16(gB0 + k0, lB0);
    gload16(gB1 + k0, lB1);
    __syncthreads();
    bf16x8 af[4], bfr[4];
#pragma unroll
    for (int i = 0; i < 4; i++)
      af[i] = *(const bf16x8*)(As + (wm + i * 16 + l15) * 32 + quad * 8);
#pragma unroll
    for (int j = 0; j < 4; j++)
      bfr[j] = *(const bf16x8*)(Bs + (wn + j * 16 + l15) * 32 + quad * 8);
#pragma unroll
    for (int i = 0; i < 4; i++)
#pragma unroll
      for (int j = 0; j < 4; j++)
        acc[i][j] = __builtin_amdgcn_mfma_f32_16x16x32_bf16(af[i], bfr[j], acc[i][j], 0, 0, 0);
  }

#pragma unroll
  for (int j = 0; j < 4; j++) {
    const int col = n0 + wn + j * 16 + l15;
    const float bvv = bias[col];
#pragma unroll
    for (int i = 0; i < 4; i++) {
      const int row0 = m0 + wm + i * 16 + quad * 4;
#pragma unroll
      for (int r = 0; r < 4; r++)
        C[(size_t)(row0 + r) * HID + col] = acc[i][j][r] + bvv;
    }
  }
}

// ===================== legacy fp32-staging GEMM (fallback plan) =====================
__device__ __forceinline__ void stage_tile(unsigned short* s, const float* g, int ldg, int tid) {
#pragma unroll
  for (int i = 0; i < 4; i++) {
    int c = i * 256 + tid;
    int row = c >> 3;
    int col = (c & 7) * 4;
    const float4 v = *(const float4*)(g + (size_t)row * ldg + col);
    ushort4 hv;
    hv.x = f2bs(v.x); hv.y = f2bs(v.y); hv.z = f2bs(v.z); hv.w = f2bs(v.w);
    *(ushort4*)(s + c * 4) = hv;
  }
}
__device__ __forceinline__ void stage_tile(unsigned short* s, const unsigned short* g, int ldg, int tid) {
#pragma unroll
  for (int i = 0; i < 2; i++) {
    int c = i * 256 + tid;
    int row = c >> 2;
    int col = (c & 3) * 8;
    const uint4 v = *(const uint4*)(g + (size_t)row * ldg + col);
    *(uint4*)(s + c * 8) = v;
  }
}

template <typename TA, int MODE>
__global__ __launch_bounds__(256) void gemm_bt(const TA* __restrict__ A, const float* __restrict__ W,
                                               const float* __restrict__ bias, void* __restrict__ Cp,
                                               float oscale, int M, int N, int K) {
  __shared__ unsigned short As[128 * 32];
  __shared__ unsigned short Bs[128 * 32];
  const int nb = N >> 7;
  const int m0 = (blockIdx.x / nb) << 7;
  const int n0 = (blockIdx.x % nb) << 7;
  const int tid = threadIdx.x;
  const int lane = tid & 63, wave = tid >> 6;
  const int quad = lane >> 4, l15 = lane & 15;
  const int wm = ((wave >> 1) << 6), wn = ((wave & 1) << 6);

  f32x4 acc[4][4] = {};

  for (int k0 = 0; k0 < K; k0 += 32) {
    __syncthreads();
    stage_tile(As, A + (size_t)m0 * K + k0, K, tid);
    stage_tile(Bs, W + (size_t)n0 * K + k0, K, tid);
    __syncthreads();
    bf16x8 af[4], bfr[4];
#pragma unroll
    for (int i = 0; i < 4; i++)
      af[i] = *(const bf16x8*)(As + (wm + i * 16 + l15) * 32 + quad * 8);
#pragma unroll
    for (int j = 0; j < 4; j++)
      bfr[j] = *(const bf16x8*)(Bs + (wn + j * 16 + l15) * 32 + quad * 8);
#pragma unroll
    for (int i = 0; i < 4; i++)
#pragma unroll
      for (int j = 0; j < 4; j++)
        acc[i][j] = __builtin_amdgcn_mfma_f32_16x16x32_bf16(af[i], bfr[j], acc[i][j], 0, 0, 0);
  }

#pragma unroll
  for (int j = 0; j < 4; j++) {
    const int col = n0 + wn + j * 16 + l15;
    const float bvv = bias[col];
    if constexpr (MODE == 0) {
      float* outp = (float*)Cp;
#pragma unroll
      for (int i = 0; i < 4; i++) {
        const int row0 = m0 + wm + i * 16 + quad * 4;
#pragma unroll
        for (int r = 0; r < 4; r++)
          outp[(size_t)(row0 + r) * N + col] = acc[i][j][r] + bvv;
      }
    } else if constexpr (MODE == 1) {
      unsigned short* outp = (unsigned short*)Cp;
      const int hh = col >> 6, d = col & 63;
#pragma unroll
      for (int i = 0; i < 4; i++) {
        const int row0 = m0 + wm + i * 16 + quad * 4;
        const int bb = row0 >> 11, s0 = row0 & 2047;
        const size_t base = ((size_t)(bb * NHEAD + hh)) * SS * HDIM + (size_t)s0 * HDIM + d;
#pragma unroll
        for (int r = 0; r < 4; r++)
          outp[base + (size_t)r * HDIM] = f2bs((acc[i][j][r] + bvv) * oscale);
      }
    } else {
      unsigned short* outp = (unsigned short*)Cp;
      const int hh = col >> 6, d = col & 63;
#pragma unroll
      for (int i = 0; i < 4; i++) {
        const int row0 = m0 + wm + i * 16 + quad * 4;
        const int bb = row0 >> 11, s0 = row0 & 2047;
        ushort4 pk;
        pk.x = f2bs(acc[i][j][0] + bvv);
        pk.y = f2bs(acc[i][j][1] + bvv);
        pk.z = f2bs(acc[i][j][2] + bvv);
        pk.w = f2bs(acc[i][j][3] + bvv);
        *(ushort4*)&outp[((size_t)(bb * NHEAD + hh)) * HDIM * SS + (size_t)d * SS + s0] = pk;
      }
    }
  }
}

// ===================== flash attention v11: 256-thr/4-wave blocks, 4 barrier groups/CU =====================
// v10's loop body verbatim; only the block topology changes. 1024 blocks x 256 threads
// (4 waves, 128 q rows per block) -> 4 blocks/CU (LDS 4x32KB=128KB). Four INDEPENDENT
// barrier groups per CU instead of two: when one block drains vmcnt at its barrier,
// three others issue MFMA (m114 wave-level overlap at barrier-group granularity).
// Per-wave work identical (32 q rows x full KV). Staging split into 8 gload16/iter;
// row-group offsets are multiples of 8 (K) / 16 (V) so the swizzle algebra is unchanged.
// Same-bh blocks remain 64 apart -> same XCD (64%8==0), K/V L2 locality preserved.
__global__ __launch_bounds__(256, 4) void attn_v11(const unsigned short* __restrict__ q,
                                                   const unsigned short* __restrict__ k,
                                                   const unsigned short* __restrict__ vt,
                                                   const float* __restrict__ mvec8,
                                                   unsigned short* __restrict__ ctx) {
  __shared__ unsigned short Ks[KVB * HDIM];    // [kv=128][d=64] 16KB, content swizzled ((row&7)<<4)
  __shared__ unsigned short Vts[HDIM * KVB];   // [d=64][kv=128] 16KB, content swizzled ((row&15)<<4)

  const int bid = blockIdx.x;
  const int qt = bid >> 6;            // 16 q-tiles of 128 rows
  const int bh = bid & 63;
  const int bI = bh >> 4, h = bh & 15;
  const int tid = threadIdx.x;
  const int wave = tid >> 6, lane = tid & 63;
  const int l31 = lane & 31, hi = lane >> 5;
  const int q0 = qt * 128 + wave * 32;
  const int kswz = (l31 & 7) << 4;    // K read swizzle (row&7 == l31&7 for frag rows)
  const int vswz = (l31 & 15) << 4;   // V read swizzle (row&15 == l31&15: rows l31, 32+l31)

  // Q fragments (B operand of S^T = K Q^T): row q0+l31, d = 16*ks + 8*hi + 0..7
  const unsigned short* qb = q + ((size_t)bh * SS + q0 + l31) * HDIM + 8 * hi;
  bf16x8 qf[4];
#pragma unroll
  for (int ks = 0; ks < 4; ks++) qf[ks] = *(const bf16x8*)(qb + 16 * ks);

  bf16x8 ones;
#pragma unroll
  for (int i = 0; i < 8; i++) ones[i] = (short)0x3F80;   // bf16 1.0

  f32x16 O0 = {}, O1 = {}, Lm = {};

  // --- staging: global_load_lds, pre-swizzled source, linear LDS dest (256 thr = 4KB/call) ---
  // K: 4 calls, 32 rows each. Thread t: row kr=t>>3 (+32c), slot kc=t&7 of 8x16B per 128B row.
  const int kr = tid >> 3, kc = tid & 7;
  const unsigned short* ksrc = k + (size_t)bh * SS * HDIM + (size_t)kr * HDIM + ((kc ^ (kr & 7)) << 3);
  // V: 4 calls, 16 rows each. Thread t: row vr=t>>4 (+16c), slot vc=t&15 of 16x16B per 256B row.
  const int vr = tid >> 4, vc = tid & 15;
  const unsigned short* vsrc = vt + (size_t)bh * HDIM * SS + (size_t)vr * SS + ((vc ^ (vr & 15)) << 3);
  // LDS dest: per call c, wave-uniform base = c*4096B + wave*1024B (lane*16 implicit)
  const int wofs = wave * 512;   // elements (1024B)

  const float* mvp = mvec8 + (size_t)bI * SS + 4 * hi;

  for (int kb = 0; kb < SS / KVB; kb++) {
    __syncthreads();   // all waves done reading previous tile
    {
      const unsigned short* kg = ksrc + (size_t)kb * KVB * HDIM;
      const unsigned short* vg = vsrc + (size_t)kb * KVB;
#pragma unroll
      for (int c = 0; c < 4; c++)
        gload16(kg + (size_t)c * 32 * HDIM, Ks + c * 2048 + wofs);
#pragma unroll
      for (int c = 0; c < 4; c++)
        gload16(vg + (size_t)c * 16 * SS, Vts + c * 2048 + wofs);
    }
    __syncthreads();   // compiler drains vmcnt before barrier -> tile visible

    const float* mrow = mvp + kb * KVB;
#pragma unroll
    for (int mt = 0; mt < 4; mt++) {
      // C-init = log2-domain mask term; C rows kv = 32*mt + (r&3)+8*(r>>2)+4*hi
      f32x16 acc;
#pragma unroll
      for (int j = 0; j < 4; j++) {
        f32x4 m4 = *(const f32x4*)(mrow + mt * 32 + j * 8);
        acc[4 * j + 0] = m4[0];
        acc[4 * j + 1] = m4[1];
        acc[4 * j + 2] = m4[2];
        acc[4 * j + 3] = m4[3];
      }
      const char* kbase = (const char*)Ks + (mt * 32 + l31) * 128;
      __builtin_amdgcn_s_setprio(1);
#pragma unroll
      for (int ks = 0; ks < 4; ks++) {
        bf16x8 kf = *(const bf16x8*)(kbase + (((ks << 5) + (hi << 4)) ^ kswz));
        acc = __builtin_amdgcn_mfma_f32_32x32x16_bf16(kf, qf[ks], acc, 0, 0, 0);
      }
      __builtin_amdgcn_s_setprio(0);
      // P = 2^acc: single v_exp_f32 per element (all scales/shift pre-folded)
#pragma unroll
      for (int r = 0; r < 16; r++) acc[r] = __builtin_amdgcn_exp2f(acc[r]);
      // select-free pack (permlane32_swap semantics pinned by v6/v8):
      // swap(A,B): A <- {A.lo32, B.lo32}, B <- {A.hi32, B.hi32}
      unsigned c0, c1, c2, c3, c4, c5, c6, c7;
      asm("v_cvt_pk_bf16_f32 %0, %1, %2" : "=v"(c0) : "v"(acc[0]), "v"(acc[1]));
      asm("v_cvt_pk_bf16_f32 %0, %1, %2" : "=v"(c1) : "v"(acc[2]), "v"(acc[3]));
      asm("v_cvt_pk_bf16_f32 %0, %1, %2" : "=v"(c2) : "v"(acc[4]), "v"(acc[5]));
      asm("v_cvt_pk_bf16_f32 %0, %1, %2" : "=v"(c3) : "v"(acc[6]), "v"(acc[7]));
      asm("v_cvt_pk_bf16_f32 %0, %1, %2" : "=v"(c4) : "v"(acc[8]), "v"(acc[9]));
      asm("v_cvt_pk_bf16_f32 %0, %1, %2" : "=v"(c5) : "v"(acc[10]), "v"(acc[11]));
      asm("v_cvt_pk_bf16_f32 %0, %1, %2" : "=v"(c6) : "v"(acc[12]), "v"(acc[13]));
      asm("v_cvt_pk_bf16_f32 %0, %1, %2" : "=v"(c7) : "v"(acc[14]), "v"(acc[15]));
      asm volatile("v_permlane32_swap_b32 %0, %1" : "+v"(c0), "+&v"(c2));
      asm volatile("v_permlane32_swap_b32 %0, %1" : "+v"(c1), "+&v"(c3));
      asm volatile("v_permlane32_swap_b32 %0, %1" : "+v"(c4), "+&v"(c6));
      asm volatile("v_permlane32_swap_b32 %0, %1" : "+v"(c5), "+&v"(c7));
      u32x4 pa4, pb4;
      pa4[0] = c0; pa4[1] = c1; pa4[2] = c2; pa4[3] = c3;
      pb4[0] = c4; pb4[1] = c5; pb4[2] = c6; pb4[3] = c7;
      bf16x8 pa = __builtin_bit_cast(bf16x8, pa4);
      bf16x8 pb = __builtin_bit_cast(bf16x8, pb4);

      // PV for this sub-tile: k-slices ks=2mt (pa), 2mt+1 (pb). V rows 256B, vswz XOR.
      const int ca = ((2 * mt) << 5) + (hi << 4);
      const int cb = ((2 * mt + 1) << 5) + (hi << 4);
      const char* vb0 = (const char*)Vts + l31 * 256;
      const char* vb1 = (const char*)Vts + (32 + l31) * 256;
      __builtin_amdgcn_s_setprio(1);
      {
        bf16x8 vfa0 = *(const bf16x8*)(vb0 + (ca ^ vswz));
        O0 = __builtin_amdgcn_mfma_f32_32x32x16_bf16(pa, vfa0, O0, 0, 0, 0);
        bf16x8 vfa1 = *(const bf16x8*)(vb1 + (ca ^ vswz));
        O1 = __builtin_amdgcn_mfma_f32_32x32x16_bf16(pa, vfa1, O1, 0, 0, 0);
        Lm = __builtin_amdgcn_mfma_f32_32x32x16_bf16(pa, ones, Lm, 0, 0, 0);
        bf16x8 vfb0 = *(const bf16x8*)(vb0 + (cb ^ vswz));
        O0 = __builtin_amdgcn_mfma_f32_32x32x16_bf16(pb, vfb0, O0, 0, 0, 0);
        bf16x8 vfb1 = *(const bf16x8*)(vb1 + (cb ^ vswz));
        O1 = __builtin_amdgcn_mfma_f32_32x32x16_bf16(pb, vfb1, O1, 0, 0, 0);
        Lm = __builtin_amdgcn_mfma_f32_32x32x16_bf16(pb, ones, Lm, 0, 0, 0);
      }
      __builtin_amdgcn_s_setprio(0);
    }
  }

  // Lm[r] = row sum for q = qp(r) (all lanes equal across cols) — same mapping as O0[r]
#pragma unroll
  for (int r = 0; r < 16; r++) {
    const float iv = __builtin_amdgcn_rcpf(Lm[r]);
    const int qp = (r & 3) + 8 * (r >> 2) + 4 * hi;
    const size_t row = (size_t)bI * SS + q0 + qp;
    ctx[row * HID + h * 64 + l31] = f2bs(O0[r] * iv);
    ctx[row * HID + h * 64 + 32 + l31] = f2bs(O1[r] * iv);
  }
}

extern "C" void kernel_launch(void* const* d_in, const int* in_sizes, int n_in,
                              void* d_out, int out_size, void* d_ws, size_t ws_size,
                              hipStream_t stream) {
  const float* query = (const float*)d_in[0];
  const float* key_  = (const float*)d_in[1];
  const float* value = (const float*)d_in[2];
  const float* mask  = (const float*)d_in[3];
  const float* Wq = (const float*)d_in[4];
  const float* bq = (const float*)d_in[5];
  const float* Wk = (const float*)d_in[6];
  const float* bk = (const float*)d_in[7];
  const float* Wv = (const float*)d_in[8];
  const float* bv = (const float*)d_in[9];
  const float* Wo = (const float*)d_in[10];
  const float* bo = (const float*)d_in[11];
  float* out = (float*)d_out;

  const size_t ME = (size_t)MTOK * HID;
  const size_t HH = (size_t)HID * HID;
  const size_t needA = (6 * ME + 4 * HH) * 2 + (size_t)BB * SS * 4;

  dim3 blk(256);

  if (ws_size >= needA) {
    unsigned short* xq   = (unsigned short*)d_ws;
    unsigned short* xk   = xq + ME;
    unsigned short* xv   = xk + ME;
    unsigned short* qhm  = xv + ME;   // [B,NH,S,64] (Q pre-scaled by 0.125*log2e)
    unsigned short* khm  = qhm + ME;  // [B,NH,S,64]
    unsigned short* vth  = khm + ME;  // [B,NH,64,S]
    unsigned short* wcat = vth + ME;  // Wq,Wk,Wv bf16
    unsigned short* wobf = wcat + 3 * HH;
    float* mvec8         = (float*)(wobf + HH);  // [B,S] log2-domain mask C-init
    unsigned short* cx   = xq;        // alias: xq dead after qkv_gemm

    cvt_all<<<3592, blk, 0, stream>>>(query, key_, value, Wq, Wk, Wv, Wo, mask,
                                      xq, xk, xv, wcat, wobf, mvec8);
    qkv_gemm<<<64 * 24, blk, 0, stream>>>(xq, xk, xv, wcat, bq, bk, bv, qhm, khm, vth);
    attn_v11<<<BB * NHEAD * (SS / 128), blk, 0, stream>>>(qhm, khm, vth, mvec8, cx);
    out_gemm<<<64 * 8, blk, 0, stream>>>(cx, wobf, bo, out);
  } else {
    unsigned short* qhm = (unsigned short*)d_ws;
    unsigned short* khm = qhm + ME;
    unsigned short* vth = khm + ME;
    unsigned short* cx  = vth + ME;
    float* mvec8f       = (float*)(cx + ME);
    const int gblocks = (MTOK / 128) * (HID / 128);  // 512

    prep_mask<<<8, blk, 0, stream>>>(mask, mvec8f);
    gemm_bt<float, 1><<<gblocks, blk, 0, stream>>>(query, Wq, bq, qhm, QSCALE, MTOK, HID, HID);
    gemm_bt<float, 1><<<gblocks, blk, 0, stream>>>(key_, Wk, bk, khm, 1.0f, MTOK, HID, HID);
    gemm_bt<float, 2><<<gblocks, blk, 0, stream>>>(value, Wv, bv, vth, 1.0f, MTOK, HID, HID);
    attn_v11<<<BB * NHEAD * (SS / 128), blk, 0, stream>>>(qhm, khm, vth, mvec8f, cx);
    gemm_bt<unsigned short, 0><<<gblocks, blk, 0, stream>>>(cx, Wo, bo, out, 1.0f, MTOK, HID, HID);
  }
}

// Round 8
// 354.967 us; speedup vs baseline: 1.0177x; 1.0177x over previous
//
#include <hip/hip_runtime.h>
#include <hip/hip_bf16.h>

#define HID 1024
#define NHEAD 16
#define HDIM 64
#define BB 4
#define SS 2048
#define MTOK (BB * SS)   // 8192 tokens
#define KVB 128

// 0.125 * log2(e): folded into Q at the qkv epilogue so attn softmax is a single v_exp_f32 (2^x)
#define QSCALE 0.18033688011112042f

typedef __attribute__((ext_vector_type(8))) short bf16x8;
typedef __attribute__((ext_vector_type(4))) float f32x4;
typedef __attribute__((ext_vector_type(16))) float f32x16;
typedef __attribute__((ext_vector_type(4))) unsigned int u32x4;

__device__ __forceinline__ unsigned short f2bs(float f) {
  __hip_bfloat16 h = __float2bfloat16(f);
  unsigned short u;
  __builtin_memcpy(&u, &h, 2);
  return u;
}

// async global->LDS, 16B per lane. LDS dest = wave-uniform base + lane*16.
__device__ __forceinline__ void gload16(const void* g, void* l) {
  __builtin_amdgcn_global_load_lds((__attribute__((address_space(1))) const void*)g,
                                   (__attribute__((address_space(3))) void*)l, 16, 0, 0);
}

// ===================== conversion pass (fp32 -> bf16, + mask prep) =====================
__global__ __launch_bounds__(256) void cvt_all(
    const float* __restrict__ s_q, const float* __restrict__ s_k, const float* __restrict__ s_v,
    const float* __restrict__ wq, const float* __restrict__ wk, const float* __restrict__ wv,
    const float* __restrict__ wo, const float* __restrict__ mask,
    unsigned short* __restrict__ xq, unsigned short* __restrict__ xk, unsigned short* __restrict__ xv,
    unsigned short* __restrict__ wcat, unsigned short* __restrict__ wobf,
    float* __restrict__ mvec8) {
  const int bid = blockIdx.x;
  if (bid >= 3584) {
    // mvec8[b][s] = ((1-mask)*(-10000) - 8) * log2(e)   (C-init for QK MFMA, log2-domain)
    const int i = (bid - 3584) * 1024 + threadIdx.x * 4;
    float4 f = *(const float4*)(mask + i);
    float4 o;
    o.x = (f.x - 1.0f) * 14426.9504f - 11.5415603f;
    o.y = (f.y - 1.0f) * 14426.9504f - 11.5415603f;
    o.z = (f.z - 1.0f) * 14426.9504f - 11.5415603f;
    o.w = (f.w - 1.0f) * 14426.9504f - 11.5415603f;
    *(float4*)(mvec8 + i) = o;
    return;
  }
  const float* src;
  unsigned short* dst;
  size_t off;
  if (bid < 3072) {
    int s = bid >> 10;
    src = (s == 0 ? s_q : (s == 1 ? s_k : s_v));
    dst = (s == 0 ? xq : (s == 1 ? xk : xv));
    off = (size_t)(bid & 1023) * 8192;
  } else {
    int s = (bid - 3072) >> 7;
    src = (s == 0 ? wq : (s == 1 ? wk : (s == 2 ? wv : wo)));
    dst = (s < 3 ? wcat + (size_t)s * HID * HID : wobf);
    off = (size_t)((bid - 3072) & 127) * 8192;
  }
  src += off;
  dst += off;
  const int t = threadIdx.x;
#pragma unroll
  for (int i = 0; i < 8; i++) {
    float4 f = *(const float4*)(src + (size_t)(i * 256 + t) * 4);
    ushort4 h;
    h.x = f2bs(f.x); h.y = f2bs(f.y); h.z = f2bs(f.z); h.w = f2bs(f.w);
    *(ushort4*)(dst + (size_t)(i * 256 + t) * 4) = h;
  }
}

// standalone mask prep (fallback path)
__global__ __launch_bounds__(256) void prep_mask(const float* __restrict__ mask,
                                                 float* __restrict__ mvec8) {
  const int i = blockIdx.x * 1024 + threadIdx.x * 4;
  float4 f = *(const float4*)(mask + i);
  float4 o;
  o.x = (f.x - 1.0f) * 14426.9504f - 11.5415603f;
  o.y = (f.y - 1.0f) * 14426.9504f - 11.5415603f;
  o.z = (f.z - 1.0f) * 14426.9504f - 11.5415603f;
  o.w = (f.w - 1.0f) * 14426.9504f - 11.5415603f;
  *(float4*)(mvec8 + i) = o;
}

// ===================== fused QKV GEMM (bf16, global_load_lds) =====================
__global__ __launch_bounds__(256) void qkv_gemm(
    const unsigned short* __restrict__ xq, const unsigned short* __restrict__ xk,
    const unsigned short* __restrict__ xv, const unsigned short* __restrict__ wcat,
    const float* __restrict__ bq, const float* __restrict__ bk, const float* __restrict__ bv,
    unsigned short* __restrict__ qhm, unsigned short* __restrict__ khm,
    unsigned short* __restrict__ vth) {
  __shared__ unsigned short As[128 * 32];
  __shared__ unsigned short Bs[128 * 32];
  const int bid = blockIdx.x;
  const int mt = bid / 24, nt = bid % 24;
  const int sel = nt >> 3;
  const int m0 = mt << 7, n0 = (nt & 7) << 7;
  const int tid = threadIdx.x;
  const int lane = tid & 63, wave = tid >> 6;
  const int quad = lane >> 4, l15 = lane & 15;
  const int wm = ((wave >> 1) << 6), wn = ((wave & 1) << 6);

  const unsigned short* A = (sel == 0 ? xq : (sel == 1 ? xk : xv));
  const unsigned short* W = wcat + (size_t)sel * HID * HID;
  const float* bias = (sel == 0 ? bq : (sel == 1 ? bk : bv));
  const float osc = (sel == 0 ? QSCALE : 1.0f);

  const int c0 = wave * 128 + lane;
  const int c1 = c0 + 64;
  const unsigned short* gA0 = A + (size_t)(m0 + (c0 >> 2)) * HID + (c0 & 3) * 8;
  const unsigned short* gA1 = A + (size_t)(m0 + (c1 >> 2)) * HID + (c1 & 3) * 8;
  const unsigned short* gB0 = W + (size_t)(n0 + (c0 >> 2)) * HID + (c0 & 3) * 8;
  const unsigned short* gB1 = W + (size_t)(n0 + (c1 >> 2)) * HID + (c1 & 3) * 8;
  unsigned short* lA0 = As + (size_t)(wave * 128) * 8;
  unsigned short* lA1 = lA0 + 64 * 8;
  unsigned short* lB0 = Bs + (size_t)(wave * 128) * 8;
  unsigned short* lB1 = lB0 + 64 * 8;

  f32x4 acc[4][4] = {};

  for (int k0 = 0; k0 < HID; k0 += 32) {
    __syncthreads();
    gload16(gA0 + k0, lA0);
    gload16(gA1 + k0, lA1);
    gload16(gB0 + k0, lB0);
    gload16(gB1 + k0, lB1);
    __syncthreads();
    bf16x8 af[4], bfr[4];
#pragma unroll
    for (int i = 0; i < 4; i++)
      af[i] = *(const bf16x8*)(As + (wm + i * 16 + l15) * 32 + quad * 8);
#pragma unroll
    for (int j = 0; j < 4; j++)
      bfr[j] = *(const bf16x8*)(Bs + (wn + j * 16 + l15) * 32 + quad * 8);
#pragma unroll
    for (int i = 0; i < 4; i++)
#pragma unroll
      for (int j = 0; j < 4; j++)
        acc[i][j] = __builtin_amdgcn_mfma_f32_16x16x32_bf16(af[i], bfr[j], acc[i][j], 0, 0, 0);
  }

#pragma unroll
  for (int j = 0; j < 4; j++) {
    const int col = n0 + wn + j * 16 + l15;
    const float bvv = bias[col];
    const int hh = col >> 6, d = col & 63;
    if (sel < 2) {
      unsigned short* outp = (sel == 0 ? qhm : khm);
#pragma unroll
      for (int i = 0; i < 4; i++) {
        const int row0 = m0 + wm + i * 16 + quad * 4;
        const int bb = row0 >> 11, s0 = row0 & 2047;
        const size_t base = ((size_t)(bb * NHEAD + hh)) * SS * HDIM + (size_t)s0 * HDIM + d;
#pragma unroll
        for (int r = 0; r < 4; r++)
          outp[base + (size_t)r * HDIM] = f2bs((acc[i][j][r] + bvv) * osc);
      }
    } else {
#pragma unroll
      for (int i = 0; i < 4; i++) {
        const int row0 = m0 + wm + i * 16 + quad * 4;
        const int bb = row0 >> 11, s0 = row0 & 2047;
        ushort4 pk;
        pk.x = f2bs(acc[i][j][0] + bvv);
        pk.y = f2bs(acc[i][j][1] + bvv);
        pk.z = f2bs(acc[i][j][2] + bvv);
        pk.w = f2bs(acc[i][j][3] + bvv);
        *(ushort4*)&vth[((size_t)(bb * NHEAD + hh)) * HDIM * SS + (size_t)d * SS + s0] = pk;
      }
    }
  }
}

// ===================== out-proj GEMM (bf16 A/W, fp32 out) =====================
__global__ __launch_bounds__(256) void out_gemm(const unsigned short* __restrict__ A,
                                                const unsigned short* __restrict__ W,
                                                const float* __restrict__ bias,
                                                float* __restrict__ C) {
  __shared__ unsigned short As[128 * 32];
  __shared__ unsigned short Bs[128 * 32];
  const int bid = blockIdx.x;
  const int mt = bid >> 3, nt = bid & 7;
  const int m0 = mt << 7, n0 = nt << 7;
  const int tid = threadIdx.x;
  const int lane = tid & 63, wave = tid >> 6;
  const int quad = lane >> 4, l15 = lane & 15;
  const int wm = ((wave >> 1) << 6), wn = ((wave & 1) << 6);

  const int c0 = wave * 128 + lane;
  const int c1 = c0 + 64;
  const unsigned short* gA0 = A + (size_t)(m0 + (c0 >> 2)) * HID + (c0 & 3) * 8;
  const unsigned short* gA1 = A + (size_t)(m0 + (c1 >> 2)) * HID + (c1 & 3) * 8;
  const unsigned short* gB0 = W + (size_t)(n0 + (c0 >> 2)) * HID + (c0 & 3) * 8;
  const unsigned short* gB1 = W + (size_t)(n0 + (c1 >> 2)) * HID + (c1 & 3) * 8;
  unsigned short* lA0 = As + (size_t)(wave * 128) * 8;
  unsigned short* lA1 = lA0 + 64 * 8;
  unsigned short* lB0 = Bs + (size_t)(wave * 128) * 8;
  unsigned short* lB1 = lB0 + 64 * 8;

  f32x4 acc[4][4] = {};

  for (int k0 = 0; k0 < HID; k0 += 32) {
    __syncthreads();
    gload16(gA0 + k0, lA0);
    gload16(gA1 + k0, lA1);
    gload16(gB0 + k0, lB0);
    gload16(gB1 + k0, lB1);
    __syncthreads();
    bf16x8 af[4], bfr[4];
#pragma unroll
    for (int i = 0; i < 4; i++)
      af[i] = *(const bf16x8*)(As + (wm + i * 16 + l15) * 32 + quad * 8);
#pragma unroll
    for (int j = 0; j < 4; j++)
      bfr[j] = *(const bf16x8*)(Bs + (wn + j * 16 + l15) * 32 + quad * 8);
#pragma unroll
    for (int i = 0; i < 4; i++)
#pragma unroll
      for (int j = 0; j < 4; j++)
        acc[i][j] = __builtin_amdgcn_mfma_f32_16x16x32_bf16(af[i], bfr[j], acc[i][j], 0, 0, 0);
  }

#pragma unroll
  for (int j = 0; j < 4; j++) {
    const int col = n0 + wn + j * 16 + l15;
    const float bvv = bias[col];
#pragma unroll
    for (int i = 0; i < 4; i++) {
      const int row0 = m0 + wm + i * 16 + quad * 4;
#pragma unroll
      for (int r = 0; r < 4; r++)
        C[(size_t)(row0 + r) * HID + col] = acc[i][j][r] + bvv;
    }
  }
}

// ===================== legacy fp32-staging GEMM (fallback plan) =====================
__device__ __forceinline__ void stage_tile(unsigned short* s, const float* g, int ldg, int tid) {
#pragma unroll
  for (int i = 0; i < 4; i++) {
    int c = i * 256 + tid;
    int row = c >> 3;
    int col = (c & 7) * 4;
    const float4 v = *(const float4*)(g + (size_t)row * ldg + col);
    ushort4 hv;
    hv.x = f2bs(v.x); hv.y = f2bs(v.y); hv.z = f2bs(v.z); hv.w = f2bs(v.w);
    *(ushort4*)(s + c * 4) = hv;
  }
}
__device__ __forceinline__ void stage_tile(unsigned short* s, const unsigned short* g, int ldg, int tid) {
#pragma unroll
  for (int i = 0; i < 2; i++) {
    int c = i * 256 + tid;
    int row = c >> 2;
    int col = (c & 3) * 8;
    const uint4 v = *(const uint4*)(g + (size_t)row * ldg + col);
    *(uint4*)(s + c * 8) = v;
  }
}

template <typename TA, int MODE>
__global__ __launch_bounds__(256) void gemm_bt(const TA* __restrict__ A, const float* __restrict__ W,
                                               const float* __restrict__ bias, void* __restrict__ Cp,
                                               float oscale, int M, int N, int K) {
  __shared__ unsigned short As[128 * 32];
  __shared__ unsigned short Bs[128 * 32];
  const int nb = N >> 7;
  const int m0 = (blockIdx.x / nb) << 7;
  const int n0 = (blockIdx.x % nb) << 7;
  const int tid = threadIdx.x;
  const int lane = tid & 63, wave = tid >> 6;
  const int quad = lane >> 4, l15 = lane & 15;
  const int wm = ((wave >> 1) << 6), wn = ((wave & 1) << 6);

  f32x4 acc[4][4] = {};

  for (int k0 = 0; k0 < K; k0 += 32) {
    __syncthreads();
    stage_tile(As, A + (size_t)m0 * K + k0, K, tid);
    stage_tile(Bs, W + (size_t)n0 * K + k0, K, tid);
    __syncthreads();
    bf16x8 af[4], bfr[4];
#pragma unroll
    for (int i = 0; i < 4; i++)
      af[i] = *(const bf16x8*)(As + (wm + i * 16 + l15) * 32 + quad * 8);
#pragma unroll
    for (int j = 0; j < 4; j++)
      bfr[j] = *(const bf16x8*)(Bs + (wn + j * 16 + l15) * 32 + quad * 8);
#pragma unroll
    for (int i = 0; i < 4; i++)
#pragma unroll
      for (int j = 0; j < 4; j++)
        acc[i][j] = __builtin_amdgcn_mfma_f32_16x16x32_bf16(af[i], bfr[j], acc[i][j], 0, 0, 0);
  }

#pragma unroll
  for (int j = 0; j < 4; j++) {
    const int col = n0 + wn + j * 16 + l15;
    const float bvv = bias[col];
    if constexpr (MODE == 0) {
      float* outp = (float*)Cp;
#pragma unroll
      for (int i = 0; i < 4; i++) {
        const int row0 = m0 + wm + i * 16 + quad * 4;
#pragma unroll
        for (int r = 0; r < 4; r++)
          outp[(size_t)(row0 + r) * N + col] = acc[i][j][r] + bvv;
      }
    } else if constexpr (MODE == 1) {
      unsigned short* outp = (unsigned short*)Cp;
      const int hh = col >> 6, d = col & 63;
#pragma unroll
      for (int i = 0; i < 4; i++) {
        const int row0 = m0 + wm + i * 16 + quad * 4;
        const int bb = row0 >> 11, s0 = row0 & 2047;
        const size_t base = ((size_t)(bb * NHEAD + hh)) * SS * HDIM + (size_t)s0 * HDIM + d;
#pragma unroll
        for (int r = 0; r < 4; r++)
          outp[base + (size_t)r * HDIM] = f2bs((acc[i][j][r] + bvv) * oscale);
      }
    } else {
      unsigned short* outp = (unsigned short*)Cp;
      const int hh = col >> 6, d = col & 63;
#pragma unroll
      for (int i = 0; i < 4; i++) {
        const int row0 = m0 + wm + i * 16 + quad * 4;
        const int bb = row0 >> 11, s0 = row0 & 2047;
        ushort4 pk;
        pk.x = f2bs(acc[i][j][0] + bvv);
        pk.y = f2bs(acc[i][j][1] + bvv);
        pk.z = f2bs(acc[i][j][2] + bvv);
        pk.w = f2bs(acc[i][j][3] + bvv);
        *(ushort4*)&outp[((size_t)(bb * NHEAD + hh)) * HDIM * SS + (size_t)d * SS + s0] = pk;
      }
    }
  }
}

// ===================== flash attention v12: dbuf + single barrier (T3 2-phase) =====================
// v10 topology (512 blocks x 512 threads) and loop body VERBATIM; only the staging/barrier
// structure changes. v10 staged between two back-to-back barriers -> full load latency
// exposed every iter (the ~24% no-issue residue). v12: double-buffered LDS (2x32KB),
// prefetch tile kb+1 into buf^1 BEFORE computing buf, ONE __syncthreads per iter.
// Race-free in plain HIP: __syncthreads drains vmcnt(0)+lgkmcnt(0) before s_barrier
// (m97-proven), so (a) the prefetch issued at top of iter kb is complete at the end-of-kb
// barrier, before iter kb+1 reads it; (b) readers of buf[x] finish before the barrier
// that precedes the next write to buf[x]. Load latency hides under ~768 cyc of MFMA.
__global__ __launch_bounds__(512, 4) void attn_v12(const unsigned short* __restrict__ q,
                                                   const unsigned short* __restrict__ k,
                                                   const unsigned short* __restrict__ vt,
                                                   const float* __restrict__ mvec8,
                                                   unsigned short* __restrict__ ctx) {
  // per buffer: K [kv=128][d=64] 16KB swizzled ((row&7)<<4) | Vt [d=64][kv=128] 16KB ((row&15)<<4)
  __shared__ char LB[2][32768];

  const int bid = blockIdx.x;
  const int qt = bid >> 6;
  const int bh = bid & 63;
  const int bI = bh >> 4, h = bh & 15;
  const int tid = threadIdx.x;
  const int wave = tid >> 6, lane = tid & 63;
  const int l31 = lane & 31, hi = lane >> 5;
  const int q0 = qt * 256 + wave * 32;
  const int kswz = (l31 & 7) << 4;    // K read swizzle (row&7 == l31&7 for frag rows)
  const int vswz = (l31 & 15) << 4;   // V read swizzle (row&15 == l31&15: rows l31, 32+l31)

  // Q fragments (B operand of S^T = K Q^T): row q0+l31, d = 16*ks + 8*hi + 0..7
  const unsigned short* qb = q + ((size_t)bh * SS + q0 + l31) * HDIM + 8 * hi;
  bf16x8 qf[4];
#pragma unroll
  for (int ks = 0; ks < 4; ks++) qf[ks] = *(const bf16x8*)(qb + 16 * ks);

  bf16x8 ones;
#pragma unroll
  for (int i = 0; i < 8; i++) ones[i] = (short)0x3F80;   // bf16 1.0

  f32x16 O0 = {}, O1 = {}, Lm = {};

  // --- staging sources: pre-swizzled global, linear LDS dest (dest byte = tid*16/group) ---
  const int kr = tid >> 3, kc = tid & 7;
  const unsigned short* ksrc = k + (size_t)bh * SS * HDIM + (size_t)kr * HDIM + ((kc ^ (kr & 7)) << 3);
  const int vr = tid >> 4, vc = tid & 15;
  const unsigned short* vsrc = vt + (size_t)bh * HDIM * SS + (size_t)vr * SS + ((vc ^ (vr & 15)) << 3);
  const int wofs = wave * 1024;   // bytes within each 8KB dest group

  const float* mvp = mvec8 + (size_t)bI * SS + 4 * hi;

  // prologue: stage tile 0 into buf 0
  {
    gload16(ksrc, LB[0] + wofs);
    gload16(ksrc + 64 * HDIM, LB[0] + 8192 + wofs);
    gload16(vsrc, LB[0] + 16384 + wofs);
    gload16(vsrc + (size_t)32 * SS, LB[0] + 24576 + wofs);
  }
  __syncthreads();   // drains vmcnt -> tile 0 visible

  for (int kb = 0; kb < SS / KVB; kb++) {
    char* base = LB[kb & 1];
    // prefetch tile kb+1 into the other buffer (async; drained by end-of-iter barrier)
    if (kb + 1 < SS / KVB) {
      char* nb = LB[(kb + 1) & 1];
      const unsigned short* kg = ksrc + (size_t)(kb + 1) * KVB * HDIM;
      const unsigned short* vg = vsrc + (size_t)(kb + 1) * KVB;
      gload16(kg, nb + wofs);
      gload16(kg + 64 * HDIM, nb + 8192 + wofs);
      gload16(vg, nb + 16384 + wofs);
      gload16(vg + (size_t)32 * SS, nb + 24576 + wofs);
    }

    const float* mrow = mvp + kb * KVB;
#pragma unroll
    for (int mt = 0; mt < 4; mt++) {
      // C-init = log2-domain mask term; C rows kv = 32*mt + (r&3)+8*(r>>2)+4*hi
      f32x16 acc;
#pragma unroll
      for (int j = 0; j < 4; j++) {
        f32x4 m4 = *(const f32x4*)(mrow + mt * 32 + j * 8);
        acc[4 * j + 0] = m4[0];
        acc[4 * j + 1] = m4[1];
        acc[4 * j + 2] = m4[2];
        acc[4 * j + 3] = m4[3];
      }
      const char* kbase = base + (mt * 32 + l31) * 128;
      __builtin_amdgcn_s_setprio(1);
#pragma unroll
      for (int ks = 0; ks < 4; ks++) {
        bf16x8 kf = *(const bf16x8*)(kbase + (((ks << 5) + (hi << 4)) ^ kswz));
        acc = __builtin_amdgcn_mfma_f32_32x32x16_bf16(kf, qf[ks], acc, 0, 0, 0);
      }
      __builtin_amdgcn_s_setprio(0);
      // P = 2^acc: single v_exp_f32 per element (all scales/shift pre-folded)
#pragma unroll
      for (int r = 0; r < 16; r++) acc[r] = __builtin_amdgcn_exp2f(acc[r]);
      // select-free pack (permlane32_swap semantics pinned by v6/v8):
      // swap(A,B): A <- {A.lo32, B.lo32}, B <- {A.hi32, B.hi32}
      unsigned c0, c1, c2, c3, c4, c5, c6, c7;
      asm("v_cvt_pk_bf16_f32 %0, %1, %2" : "=v"(c0) : "v"(acc[0]), "v"(acc[1]));
      asm("v_cvt_pk_bf16_f32 %0, %1, %2" : "=v"(c1) : "v"(acc[2]), "v"(acc[3]));
      asm("v_cvt_pk_bf16_f32 %0, %1, %2" : "=v"(c2) : "v"(acc[4]), "v"(acc[5]));
      asm("v_cvt_pk_bf16_f32 %0, %1, %2" : "=v"(c3) : "v"(acc[6]), "v"(acc[7]));
      asm("v_cvt_pk_bf16_f32 %0, %1, %2" : "=v"(c4) : "v"(acc[8]), "v"(acc[9]));
      asm("v_cvt_pk_bf16_f32 %0, %1, %2" : "=v"(c5) : "v"(acc[10]), "v"(acc[11]));
      asm("v_cvt_pk_bf16_f32 %0, %1, %2" : "=v"(c6) : "v"(acc[12]), "v"(acc[13]));
      asm("v_cvt_pk_bf16_f32 %0, %1, %2" : "=v"(c7) : "v"(acc[14]), "v"(acc[15]));
      asm volatile("v_permlane32_swap_b32 %0, %1" : "+v"(c0), "+&v"(c2));
      asm volatile("v_permlane32_swap_b32 %0, %1" : "+v"(c1), "+&v"(c3));
      asm volatile("v_permlane32_swap_b32 %0, %1" : "+v"(c4), "+&v"(c6));
      asm volatile("v_permlane32_swap_b32 %0, %1" : "+v"(c5), "+&v"(c7));
      u32x4 pa4, pb4;
      pa4[0] = c0; pa4[1] = c1; pa4[2] = c2; pa4[3] = c3;
      pb4[0] = c4; pb4[1] = c5; pb4[2] = c6; pb4[3] = c7;
      bf16x8 pa = __builtin_bit_cast(bf16x8, pa4);
      bf16x8 pb = __builtin_bit_cast(bf16x8, pb4);

      // PV for this sub-tile: k-slices ks=2mt (pa), 2mt+1 (pb). V rows 256B, vswz XOR.
      const int ca = ((2 * mt) << 5) + (hi << 4);
      const int cb = ((2 * mt + 1) << 5) + (hi << 4);
      const char* vb0 = base + 16384 + l31 * 256;
      const char* vb1 = base + 16384 + (32 + l31) * 256;
      __builtin_amdgcn_s_setprio(1);
      {
        bf16x8 vfa0 = *(const bf16x8*)(vb0 + (ca ^ vswz));
        O0 = __builtin_amdgcn_mfma_f32_32x32x16_bf16(pa, vfa0, O0, 0, 0, 0);
        bf16x8 vfa1 = *(const bf16x8*)(vb1 + (ca ^ vswz));
        O1 = __builtin_amdgcn_mfma_f32_32x32x16_bf16(pa, vfa1, O1, 0, 0, 0);
        Lm = __builtin_amdgcn_mfma_f32_32x32x16_bf16(pa, ones, Lm, 0, 0, 0);
        bf16x8 vfb0 = *(const bf16x8*)(vb0 + (cb ^ vswz));
        O0 = __builtin_amdgcn_mfma_f32_32x32x16_bf16(pb, vfb0, O0, 0, 0, 0);
        bf16x8 vfb1 = *(const bf16x8*)(vb1 + (cb ^ vswz));
        O1 = __builtin_amdgcn_mfma_f32_32x32x16_bf16(pb, vfb1, O1, 0, 0, 0);
        Lm = __builtin_amdgcn_mfma_f32_32x32x16_bf16(pb, ones, Lm, 0, 0, 0);
      }
      __builtin_amdgcn_s_setprio(0);
    }
    __syncthreads();   // drains vmcnt (prefetch done) + readers done with buf[kb&1]
  }

  // Lm[r] = row sum for q = qp(r) (all lanes equal across cols) — same mapping as O0[r]
#pragma unroll
  for (int r = 0; r < 16; r++) {
    const float iv = __builtin_amdgcn_rcpf(Lm[r]);
    const int qp = (r & 3) + 8 * (r >> 2) + 4 * hi;
    const size_t row = (size_t)bI * SS + q0 + qp;
    ctx[row * HID + h * 64 + l31] = f2bs(O0[r] * iv);
    ctx[row * HID + h * 64 + 32 + l31] = f2bs(O1[r] * iv);
  }
}

extern "C" void kernel_launch(void* const* d_in, const int* in_sizes, int n_in,
                              void* d_out, int out_size, void* d_ws, size_t ws_size,
                              hipStream_t stream) {
  const float* query = (const float*)d_in[0];
  const float* key_  = (const float*)d_in[1];
  const float* value = (const float*)d_in[2];
  const float* mask  = (const float*)d_in[3];
  const float* Wq = (const float*)d_in[4];
  const float* bq = (const float*)d_in[5];
  const float* Wk = (const float*)d_in[6];
  const float* bk = (const float*)d_in[7];
  const float* Wv = (const float*)d_in[8];
  const float* bv = (const float*)d_in[9];
  const float* Wo = (const float*)d_in[10];
  const float* bo = (const float*)d_in[11];
  float* out = (float*)d_out;

  const size_t ME = (size_t)MTOK * HID;
  const size_t HH = (size_t)HID * HID;
  const size_t needA = (6 * ME + 4 * HH) * 2 + (size_t)BB * SS * 4;

  dim3 blk(256);
  dim3 blk512(512);

  if (ws_size >= needA) {
    unsigned short* xq   = (unsigned short*)d_ws;
    unsigned short* xk   = xq + ME;
    unsigned short* xv   = xk + ME;
    unsigned short* qhm  = xv + ME;   // [B,NH,S,64] (Q pre-scaled by 0.125*log2e)
    unsigned short* khm  = qhm + ME;  // [B,NH,S,64]
    unsigned short* vth  = khm + ME;  // [B,NH,64,S]
    unsigned short* wcat = vth + ME;  // Wq,Wk,Wv bf16
    unsigned short* wobf = wcat + 3 * HH;
    float* mvec8         = (float*)(wobf + HH);  // [B,S] log2-domain mask C-init
    unsigned short* cx   = xq;        // alias: xq dead after qkv_gemm

    cvt_all<<<3592, blk, 0, stream>>>(query, key_, value, Wq, Wk, Wv, Wo, mask,
                                      xq, xk, xv, wcat, wobf, mvec8);
    qkv_gemm<<<64 * 24, blk, 0, stream>>>(xq, xk, xv, wcat, bq, bk, bv, qhm, khm, vth);
    attn_v12<<<BB * NHEAD * (SS / 256), blk512, 0, stream>>>(qhm, khm, vth, mvec8, cx);
    out_gemm<<<64 * 8, blk, 0, stream>>>(cx, wobf, bo, out);
  } else {
    unsigned short* qhm = (unsigned short*)d_ws;
    unsigned short* khm = qhm + ME;
    unsigned short* vth = khm + ME;
    unsigned short* cx  = vth + ME;
    float* mvec8f       = (float*)(cx + ME);
    const int gblocks = (MTOK / 128) * (HID / 128);  // 512

    prep_mask<<<8, blk, 0, stream>>>(mask, mvec8f);
    gemm_bt<float, 1><<<gblocks, blk, 0, stream>>>(query, Wq, bq, qhm, QSCALE, MTOK, HID, HID);
    gemm_bt<float, 1><<<gblocks, blk, 0, stream>>>(key_, Wk, bk, khm, 1.0f, MTOK, HID, HID);
    gemm_bt<float, 2><<<gblocks, blk, 0, stream>>>(value, Wv, bv, vth, 1.0f, MTOK, HID, HID);
    attn_v12<<<BB * NHEAD * (SS / 256), blk512, 0, stream>>>(qhm, khm, vth, mvec8f, cx);
    gemm_bt<unsigned short, 0><<<gblocks, blk, 0, stream>>>(cx, Wo, bo, out, 1.0f, MTOK, HID, HID);
  }
}